// Round 14
// baseline (301.229 us; speedup 1.0000x reference)
//
#include <hip/hip_runtime.h>

typedef _Float16 half8 __attribute__((ext_vector_type(8)));
typedef _Float16 half4 __attribute__((ext_vector_type(4)));
typedef float floatx4 __attribute__((ext_vector_type(4)));
typedef float floatx16 __attribute__((ext_vector_type(16)));

#define MFMA16(A,B,C) __builtin_amdgcn_mfma_f32_16x16x32_f16((A),(B),(C),0,0,0)
#define MFMA32(A,B,C) __builtin_amdgcn_mfma_f32_32x32x16_f16((A),(B),(C),0,0,0)

#define GLOAD_LDS(G, L)                                                        \
  __builtin_amdgcn_global_load_lds(                                            \
      (const __attribute__((address_space(1))) unsigned int*)(G),              \
      (__attribute__((address_space(3))) unsigned int*)(L), 16, 0, 0)

// Problem constants (B=4, S=2048, D=1024, H=16, DPH=64)

// ---------------------------------------------------------------------------
// K0: bit-pack the int32 bool mask [B,S,S] -> u32 words, TRANSPOSED layout
// p[(b*64 + w)*2048 + s] = bits for row s, keys [w*32, w*32+32).
// ---------------------------------------------------------------------------
__global__ __launch_bounds__(256) void maskpack(
    const int* __restrict__ m, unsigned int* __restrict__ p)
{
  const int w = blockIdx.x * 256 + threadIdx.x;   // 524288 words total
  const int b = w >> 17;
  const int rem = w & 131071;
  const int s = rem >> 6;
  const int wp = rem & 63;
  const int4* src = (const int4*)(m + (size_t)w * 32);
  unsigned int bits = 0;
#pragma unroll
  for (int j = 0; j < 8; ++j) {
    const int4 v = src[j];
    bits |= (v.x ? 1u : 0u) << (j * 4 + 0);
    bits |= (v.y ? 1u : 0u) << (j * 4 + 1);
    bits |= (v.z ? 1u : 0u) << (j * 4 + 2);
    bits |= (v.w ? 1u : 0u) << (j * 4 + 3);
  }
  p[((size_t)(b * 64 + wp)) * 2048 + s] = bits;
}

// ---------------------------------------------------------------------------
// K1: convert the 4 weight matrices fp32 [k][n] -> fp16 W^T [n][k]
// ---------------------------------------------------------------------------
__global__ __launch_bounds__(256) void wconv(
    const float* __restrict__ Wq, const float* __restrict__ Wk,
    const float* __restrict__ Wv, const float* __restrict__ Wo,
    _Float16* __restrict__ dst)
{
  const float* W = (blockIdx.z == 0) ? Wq : (blockIdx.z == 1) ? Wk
                  : (blockIdx.z == 2) ? Wv : Wo;
  _Float16* WT = dst + (size_t)blockIdx.z * 1024 * 1024;
  __shared__ float t[32][33];
  const int tx = threadIdx.x & 31;
  const int ty = threadIdx.x >> 5;
  const int k0 = blockIdx.x * 32, n0 = blockIdx.y * 32;
#pragma unroll
  for (int j = 0; j < 4; ++j)
    t[ty + j * 8][tx] = W[(size_t)(k0 + ty + j * 8) * 1024 + n0 + tx];
  __syncthreads();
#pragma unroll
  for (int j = 0; j < 4; ++j)
    WT[(size_t)(n0 + ty + j * 8) * 1024 + k0 + tx] = (_Float16)t[tx][ty + j * 8];
}

// ---------------------------------------------------------------------------
// K1b: fp32 [8192,1024] -> fp16 (vectorized, pure BW). Output goes into the
// ctx scratch region (free until attn runs) -> zero extra workspace.
// ---------------------------------------------------------------------------
__global__ __launch_bounds__(256) void aconv(
    const float* __restrict__ s, _Float16* __restrict__ d)
{
  const size_t i = ((size_t)blockIdx.x * 256 + threadIdx.x) * 8;
  floatx4 v0 = *(const floatx4*)(s + i);
  floatx4 v1 = *(const floatx4*)(s + i + 4);
  union { half8 v; unsigned int u[4]; } pk;
  pk.u[0] = __builtin_bit_cast(unsigned int, __builtin_amdgcn_cvt_pkrtz(v0[0], v0[1]));
  pk.u[1] = __builtin_bit_cast(unsigned int, __builtin_amdgcn_cvt_pkrtz(v0[2], v0[3]));
  pk.u[2] = __builtin_bit_cast(unsigned int, __builtin_amdgcn_cvt_pkrtz(v1[0], v1[1]));
  pk.u[3] = __builtin_bit_cast(unsigned int, __builtin_amdgcn_cvt_pkrtz(v1[2], v1[3]));
  *(half8*)(d + i) = pk.v;
}

// ---------------------------------------------------------------------------
// K2/K4: GEMM C[8192,1024] = A[8192,1024] @ W + bias, fp16 MFMA, fp32 accum.
// A is fp16 (pre-converted); BOTH operands staged via global_load_lds w16
// with pre-swizzled global source slot (lane&7)^(row&7) == swizzled-read
// layout (m97 recipe; catalog #21 both-sides-or-neither). Zero staging VALU.
// Epilogue: LDS-bounce to fully-coalesced 128B row writes.
// OP 0: out = half q_up [B,H,S,64], (acc+bias)*0.125*log2(e)
// OP 1: out = half k_up [B,H,S,64]
// OP 2: out = half vT   [B,H,64,S], s-index bits 2<->3 swapped (PV k-perm)
// OP 3: out = float d_out [8192,1024]
// ---------------------------------------------------------------------------
template <int OP>
__global__ __launch_bounds__(256) void gemm_k(
    const _Float16* __restrict__ Ah, const _Float16* __restrict__ BT,
    const float* __restrict__ bias, void* __restrict__ Cp)
{
  __shared__ __align__(16) char smem[32768];
  char* AsB = smem;            // 16KB A tile
  char* BsB = smem + 16384;    // 16KB B tile
  const int tid = threadIdx.x;
  const int lane = tid & 63;
  const int wv = tid >> 6;
  const int m0 = blockIdx.x * 128;
  const int n0 = blockIdx.y * 128;
  const int wr = (wv >> 1) * 64;
  const int wc = (wv & 1) * 64;

  floatx4 acc[4][4];
#pragma unroll
  for (int i = 0; i < 4; ++i)
#pragma unroll
    for (int j = 0; j < 4; ++j) acc[i][j] = (floatx4){0.f, 0.f, 0.f, 0.f};

  const int grow = lane >> 3;            // row within 8-row chunk
  const int gslot = (lane & 7) ^ grow;   // pre-swizzled 16B source slot

  for (int ko = 0; ko < 1024; ko += 64) {
#pragma unroll
    for (int it = 0; it < 4; ++it) {
      const int c = wv * 4 + it;         // 8-row chunk id (0..15)
      const int row = c * 8 + grow;
      GLOAD_LDS(Ah + (size_t)(m0 + row) * 1024 + ko + gslot * 8, AsB + c * 1024);
      GLOAD_LDS(BT + (size_t)(n0 + row) * 1024 + ko + gslot * 8, BsB + c * 1024);
    }
    __syncthreads();
#pragma unroll
    for (int kk = 0; kk < 64; kk += 32) {
      half8 af[4], bf[4];
#pragma unroll
      for (int mi = 0; mi < 4; ++mi) {
        const int row = wr + mi * 16 + (lane & 15);
        const int cb = (kk + (lane >> 4) * 8) * 2;
        af[mi] = *(const half8*)(AsB + row * 128 + (cb ^ ((row & 7) << 4)));
      }
#pragma unroll
      for (int ni = 0; ni < 4; ++ni) {
        const int row = wc + ni * 16 + (lane & 15);
        const int cb = (kk + (lane >> 4) * 8) * 2;
        bf[ni] = *(const half8*)(BsB + row * 128 + (cb ^ ((row & 7) << 4)));
      }
#pragma unroll
      for (int mi = 0; mi < 4; ++mi)
#pragma unroll
        for (int ni = 0; ni < 4; ++ni)
          acc[mi][ni] = MFMA16(af[mi], bf[ni], acc[mi][ni]);
    }
    __syncthreads();
  }

  // ---- LDS-bounce epilogue (coalesced 128B output runs) ----
  // acc layout: mm = m0+wr+mi*16+(lane>>4)*4+i, nn = n0+wc+ni*16+(lane&15)
  if (OP == 0 || OP == 1) {
    // stage half C[128(m)][128(n)]
#pragma unroll
    for (int ni = 0; ni < 4; ++ni) {
      const int nloc = wc + ni * 16 + (lane & 15);
      const float bvv = bias[n0 + nloc];
#pragma unroll
      for (int mi = 0; mi < 4; ++mi) {
        floatx4 c = acc[mi][ni];
        const int mb = wr + mi * 16 + (lane >> 4) * 4;
#pragma unroll
        for (int i = 0; i < 4; ++i) {
          float val = c[i] + bvv;
          if (OP == 0) val *= 0.1803368801111204f;   // (1/8)*log2(e)
          ((_Float16*)smem)[(mb + i) * 128 + nloc] = (_Float16)val;
        }
      }
    }
    __syncthreads();
    const int mloc = tid & 127, hseg = tid >> 7;
    const int batch = m0 >> 11;
    const int head = (n0 >> 6) + hseg;
    _Float16* dst = (_Float16*)Cp +
        (((size_t)(batch * 16 + head)) * 2048 + (m0 & 2047) + mloc) * 64;
    const _Float16* srcr = (const _Float16*)smem + mloc * 128 + hseg * 64;
#pragma unroll
    for (int c8 = 0; c8 < 8; ++c8) {
      const int cc = (c8 + (tid & 7)) & 7;
      *(half8*)(dst + cc * 8) = *(const half8*)(srcr + cc * 8);
    }
  } else if (OP == 2) {
    // stage half C^T[128(n=d)][128(m=s, bits2<->3 swapped)]
#pragma unroll
    for (int ni = 0; ni < 4; ++ni) {
      const int nloc = wc + ni * 16 + (lane & 15);
      const float bvv = bias[n0 + nloc];
#pragma unroll
      for (int mi = 0; mi < 4; ++mi) {
        floatx4 c = acc[mi][ni];
        const int mb = wr + mi * 16 + (lane >> 4) * 4;     // multiple of 4
        const int mp = (mb & ~0xC) | ((mb & 4) << 1) | ((mb & 8) >> 1);
        half4 w4;
        w4[0] = (_Float16)(c[0] + bvv);
        w4[1] = (_Float16)(c[1] + bvv);
        w4[2] = (_Float16)(c[2] + bvv);
        w4[3] = (_Float16)(c[3] + bvv);
        *(half4*)((_Float16*)smem + nloc * 128 + mp) = w4;
      }
    }
    __syncthreads();
    const int rn = tid & 127, sh = tid >> 7;
    const int batch = m0 >> 11;
    const int head = (n0 >> 6) + (rn >> 6);
    const int d = rn & 63;
    _Float16* dst = (_Float16*)Cp +
        (((size_t)(batch * 16 + head)) * 64 + d) * 2048 + (m0 & 2047) + sh * 64;
    const _Float16* srcr = (const _Float16*)smem + rn * 128 + sh * 64;
#pragma unroll
    for (int c8 = 0; c8 < 8; ++c8) {
      const int cc = (c8 + (tid & 7)) & 7;
      *(half8*)(dst + cc * 8) = *(const half8*)(srcr + cc * 8);
    }
  } else {
    // OP3: float out, two 32KB half-tiles [128(m)][64(n)]
#pragma unroll 1
    for (int nh = 0; nh < 2; ++nh) {
      __syncthreads();
      if (wc == nh * 64) {
#pragma unroll
        for (int ni = 0; ni < 4; ++ni) {
          const int nl = ni * 16 + (lane & 15);            // 0..63
          const float bvv = bias[n0 + nh * 64 + nl];
#pragma unroll
          for (int mi = 0; mi < 4; ++mi) {
            floatx4 c = acc[mi][ni];
            const int mb = wr + mi * 16 + (lane >> 4) * 4;
#pragma unroll
            for (int i = 0; i < 4; ++i)
              ((float*)smem)[(mb + i) * 64 + nl] = c[i] + bvv;
          }
        }
      }
      __syncthreads();
      const int mloc = tid & 127, h2 = tid >> 7;
      float* dst = (float*)Cp + (size_t)(m0 + mloc) * 1024 + n0 + nh * 64 + h2 * 32;
      const float* srcr = (const float*)smem + mloc * 64 + h2 * 32;
#pragma unroll
      for (int c4 = 0; c4 < 8; ++c4) {
        const int cc = (c4 + (tid & 7)) & 7;
        *(floatx4*)(dst + cc * 4) = *(const floatx4*)(srcr + cc * 4);
      }
    }
  }
}

// ---------------------------------------------------------------------------
// K3: flash attention, 32x32x16 MFMA, fixed-max in-register softmax.
// (unchanged from round 13 — 133 us, 517 TF)
// ---------------------------------------------------------------------------
__global__ __launch_bounds__(256) void attn_k(
    const _Float16* __restrict__ q_up, const _Float16* __restrict__ k_up,
    const _Float16* __restrict__ vT, const unsigned int* __restrict__ pmaskT,
    _Float16* __restrict__ ctx)
{
  const int tid = threadIdx.x;
  const int lane = tid & 63;
  const int wv = tid >> 6;
  const int bid = blockIdx.x;
  const int xcd = bid & 7;
  const int slot = bid >> 3;
  const int bh = xcd * 8 + (slot & 7);
  const int qc = slot >> 3;
  const int b = bh >> 4;
  const int h = bh & 15;
  const int l31 = lane & 31;
  const int hi = lane >> 5;
  const int qw = qc * 256 + wv * 64;

  __shared__ __align__(16) _Float16 Kl[2][32 * 64];   // 2 x 4KB
  __shared__ __align__(16) _Float16 Vl[2][64 * 32];   // 2 x 4KB

  const _Float16* qb = q_up + ((size_t)bh * 2048 + qw) * 64;
  const _Float16* kb = k_up + (size_t)bh * 2048 * 64;
  const _Float16* vb = vT + (size_t)bh * 64 * 2048;
  const unsigned int* mbase = pmaskT + (size_t)(b * 64) * 2048 + qw + l31;

  const int krow = tid >> 3, kseg = tid & 7;
  const int kByte = krow * 128 + ((kseg * 16) ^ ((krow & 7) << 4));
  const int vrow = tid >> 2, vseg = tid & 3;
  const int vByte = vrow * 64 + ((vseg * 16) ^ (((vrow >> 1) & 3) << 4));
  const _Float16* gK = kb + tid * 8;
  const _Float16* gV = vb + (size_t)vrow * 2048 + vseg * 8;
  char* KB = (char*)Kl;
  char* VB = (char*)Vl;

  half8 qf[2][4];
#pragma unroll
  for (int qt = 0; qt < 2; ++qt)
#pragma unroll
    for (int kk = 0; kk < 4; ++kk)
      qf[qt][kk] = *(const half8*)(qb + (size_t)(qt * 32 + l31) * 64 + kk * 16 + hi * 8);

  floatx16 O[2][2];
#pragma unroll
  for (int qt = 0; qt < 2; ++qt)
#pragma unroll
    for (int dt = 0; dt < 2; ++dt)
#pragma unroll
      for (int r = 0; r < 16; ++r) O[qt][dt][r] = 0.f;
  float lsum[2] = {0.f, 0.f};

  floatx16 zero16;
#pragma unroll
  for (int r = 0; r < 16; ++r) zero16[r] = 0.f;

  half8 stK, stV;

  auto COMPUTE = [&](int buf, int t) {
    unsigned int mw[2];
    mw[0] = mbase[(size_t)t * 2048];
    mw[1] = mbase[(size_t)t * 2048 + 32];
    half8 kf[4];
#pragma unroll
    for (int kk = 0; kk < 4; ++kk)
      kf[kk] = *(const half8*)(KB + buf * 4096 + l31 * 128 +
                               ((kk * 32 + hi * 16) ^ ((l31 & 7) << 4)));
    half8 vf[2][2];
#pragma unroll
    for (int dt = 0; dt < 2; ++dt)
#pragma unroll
      for (int kk2 = 0; kk2 < 2; ++kk2)
        vf[dt][kk2] = *(const half8*)(VB + buf * 4096 + (dt * 32 + l31) * 64 +
                                      ((kk2 * 32 + hi * 16) ^ (((l31 >> 1) & 3) << 4)));

    floatx16 s[2];
    __builtin_amdgcn_s_setprio(1);
#pragma unroll
    for (int qt = 0; qt < 2; ++qt) {
      floatx16 a;
      a = MFMA32(kf[0], qf[qt][0], zero16);
      a = MFMA32(kf[1], qf[qt][1], a);
      a = MFMA32(kf[2], qf[qt][2], a);
      s[qt] = MFMA32(kf[3], qf[qt][3], a);
    }
    __builtin_amdgcn_s_setprio(0);

#pragma unroll
    for (int qt = 0; qt < 2; ++qt) {
      const unsigned int mh = mw[qt] >> (4 * hi);
      float e[16];
#pragma unroll
      for (int m = 0; m < 4; ++m) {
        const unsigned int bm = mh >> (8 * m);
#pragma unroll
        for (int j = 0; j < 4; ++j)
          e[4 * m + j] =
              ((bm >> j) & 1u) ? 0.f : __builtin_amdgcn_exp2f(s[qt][4 * m + j]);
      }
      float u0 = (e[0] + e[1]) + (e[2] + e[3]);
      float u1 = (e[4] + e[5]) + (e[6] + e[7]);
      float u2 = (e[8] + e[9]) + (e[10] + e[11]);
      float u3 = (e[12] + e[13]) + (e[14] + e[15]);
      lsum[qt] += (u0 + u1) + (u2 + u3);

      union { half8 v; unsigned int u[4]; } p0, p1;
      p0.u[0] = __builtin_bit_cast(unsigned int, __builtin_amdgcn_cvt_pkrtz(e[0], e[1]));
      p0.u[1] = __builtin_bit_cast(unsigned int, __builtin_amdgcn_cvt_pkrtz(e[2], e[3]));
      p0.u[2] = __builtin_bit_cast(unsigned int, __builtin_amdgcn_cvt_pkrtz(e[4], e[5]));
      p0.u[3] = __builtin_bit_cast(unsigned int, __builtin_amdgcn_cvt_pkrtz(e[6], e[7]));
      p1.u[0] = __builtin_bit_cast(unsigned int, __builtin_amdgcn_cvt_pkrtz(e[8], e[9]));
      p1.u[1] = __builtin_bit_cast(unsigned int, __builtin_amdgcn_cvt_pkrtz(e[10], e[11]));
      p1.u[2] = __builtin_bit_cast(unsigned int, __builtin_amdgcn_cvt_pkrtz(e[12], e[13]));
      p1.u[3] = __builtin_bit_cast(unsigned int, __builtin_amdgcn_cvt_pkrtz(e[14], e[15]));
      __builtin_amdgcn_s_setprio(1);
#pragma unroll
      for (int dt = 0; dt < 2; ++dt) {
        O[qt][dt] = MFMA32(vf[dt][0], p0.v, O[qt][dt]);
        O[qt][dt] = MFMA32(vf[dt][1], p1.v, O[qt][dt]);
      }
      __builtin_amdgcn_s_setprio(0);
    }
  };

  stK = *(const half8*)gK;
  stV = *(const half8*)gV;
  *(half8*)(KB + kByte) = stK;
  *(half8*)(VB + vByte) = stV;
  stK = *(const half8*)(gK + 2048);
  stV = *(const half8*)(gV + 32);
  __syncthreads();

#pragma unroll 1
  for (int t = 0; t < 64; t += 2) {
    {
      *(half8*)(KB + 4096 + kByte) = stK;
      *(half8*)(VB + 4096 + vByte) = stV;
      const int tn = (t + 2 < 64) ? t + 2 : 0;
      stK = *(const half8*)(gK + (size_t)tn * 2048);
      stV = *(const half8*)(gV + tn * 32);
      COMPUTE(0, t);
      __syncthreads();
    }
    {
      *(half8*)(KB + kByte) = stK;
      *(half8*)(VB + vByte) = stV;
      const int tn = (t + 3 < 64) ? t + 3 : 0;
      stK = *(const half8*)(gK + (size_t)tn * 2048);
      stV = *(const half8*)(gV + tn * 32);
      COMPUTE(1, t + 1);
      __syncthreads();
    }
  }

#pragma unroll
  for (int qt = 0; qt < 2; ++qt) {
    const float tot = lsum[qt] + __shfl_xor(lsum[qt], 32);
    const float inv = 1.f / tot;
    const size_t rowb = ((size_t)(b * 2048 + qw + qt * 32 + l31)) * 1024 + h * 64;
#pragma unroll
    for (int dt = 0; dt < 2; ++dt) {
#pragma unroll
      for (int m = 0; m < 4; ++m) {
        half4 w4;
        w4[0] = (_Float16)(O[qt][dt][4 * m + 0] * inv);
        w4[1] = (_Float16)(O[qt][dt][4 * m + 1] * inv);
        w4[2] = (_Float16)(O[qt][dt][4 * m + 2] * inv);
        w4[3] = (_Float16)(O[qt][dt][4 * m + 3] * inv);
        *(half4*)(ctx + rowb + dt * 32 + 8 * m + 4 * hi) = w4;
      }
    }
  }
}

// ---------------------------------------------------------------------------
// Launch. Workspace (fp16 elems): WT 4M | q_up 8M | k_up 8M | vT 8M | ctx 8M
// | pmaskT 2MB. Total ~74 MB. ctx doubles as fp16-A scratch before attn.
// ---------------------------------------------------------------------------
extern "C" void kernel_launch(void* const* d_in, const int* in_sizes, int n_in,
                              void* d_out, int out_size, void* d_ws, size_t ws_size,
                              hipStream_t stream) {
  const float* key   = (const float*)d_in[0];
  const float* value = (const float*)d_in[1];
  const float* query = (const float*)d_in[2];
  const int*   mask  = (const int*)d_in[3];     // bool -> int32 per harness
  const float* Wq = (const float*)d_in[4];
  const float* bq = (const float*)d_in[5];
  const float* Wk = (const float*)d_in[6];
  const float* bk = (const float*)d_in[7];
  const float* Wv = (const float*)d_in[8];
  const float* bv = (const float*)d_in[9];
  const float* Wo = (const float*)d_in[10];
  const float* bo = (const float*)d_in[11];

  _Float16* wsp = (_Float16*)d_ws;
  _Float16* WT   = wsp;
  _Float16* q_up = wsp + (size_t)4 * 1024 * 1024;
  _Float16* k_up = q_up + (size_t)8192 * 1024;
  _Float16* vT   = k_up + (size_t)8192 * 1024;
  _Float16* ctx  = vT + (size_t)8192 * 1024;
  unsigned int* pmaskT = (unsigned int*)(ctx + (size_t)8192 * 1024);
  _Float16* ascr = ctx;   // fp16-A scratch (free until attn writes ctx)

  maskpack<<<dim3(2048), 256, 0, stream>>>(mask, pmaskT);
  wconv<<<dim3(32, 32, 4), 256, 0, stream>>>(Wq, Wk, Wv, Wo, WT);
  aconv<<<dim3(4096), 256, 0, stream>>>(query, ascr);
  gemm_k<0><<<dim3(64, 8), 256, 0, stream>>>(ascr, WT, bq, q_up);
  aconv<<<dim3(4096), 256, 0, stream>>>(key, ascr);
  gemm_k<1><<<dim3(64, 8), 256, 0, stream>>>(ascr, WT + (size_t)1024 * 1024, bk, k_up);
  aconv<<<dim3(4096), 256, 0, stream>>>(value, ascr);
  gemm_k<2><<<dim3(64, 8), 256, 0, stream>>>(ascr, WT + (size_t)2 * 1024 * 1024, bv, vT);
  attn_k<<<dim3(512), 256, 0, stream>>>(q_up, k_up, vT, pmaskT, ctx);
  gemm_k<3><<<dim3(64, 8), 256, 0, stream>>>(ctx, WT + (size_t)3 * 1024 * 1024, bo, (float*)d_out);
}

// Round 15
// 251.091 us; speedup vs baseline: 1.1997x; 1.1997x over previous
//
#include <hip/hip_runtime.h>

typedef _Float16 half8 __attribute__((ext_vector_type(8)));
typedef _Float16 half4 __attribute__((ext_vector_type(4)));
typedef float floatx4 __attribute__((ext_vector_type(4)));
typedef float floatx16 __attribute__((ext_vector_type(16)));

#define MFMA16(A,B,C) __builtin_amdgcn_mfma_f32_16x16x32_f16((A),(B),(C),0,0,0)
#define MFMA32(A,B,C) __builtin_amdgcn_mfma_f32_32x32x16_f16((A),(B),(C),0,0,0)

// Problem constants (B=4, S=2048, D=1024, H=16, DPH=64)

// ---------------------------------------------------------------------------
// K0: bit-pack the int32 bool mask [B,S,S] -> u32 words, TRANSPOSED layout
// p[(b*64 + w)*2048 + s] = bits for row s, keys [w*32, w*32+32).
// ---------------------------------------------------------------------------
__global__ __launch_bounds__(256) void maskpack(
    const int* __restrict__ m, unsigned int* __restrict__ p)
{
  const int w = blockIdx.x * 256 + threadIdx.x;   // 524288 words total
  const int b = w >> 17;
  const int rem = w & 131071;
  const int s = rem >> 6;
  const int wp = rem & 63;
  const int4* src = (const int4*)(m + (size_t)w * 32);
  unsigned int bits = 0;
#pragma unroll
  for (int j = 0; j < 8; ++j) {
    const int4 v = src[j];
    bits |= (v.x ? 1u : 0u) << (j * 4 + 0);
    bits |= (v.y ? 1u : 0u) << (j * 4 + 1);
    bits |= (v.z ? 1u : 0u) << (j * 4 + 2);
    bits |= (v.w ? 1u : 0u) << (j * 4 + 3);
  }
  p[((size_t)(b * 64 + wp)) * 2048 + s] = bits;
}

// ---------------------------------------------------------------------------
// K1: convert the 4 weight matrices fp32 [k][n] -> fp16 W^T [n][k]
// ---------------------------------------------------------------------------
__global__ __launch_bounds__(256) void wconv(
    const float* __restrict__ Wq, const float* __restrict__ Wk,
    const float* __restrict__ Wv, const float* __restrict__ Wo,
    _Float16* __restrict__ dst)
{
  const float* W = (blockIdx.z == 0) ? Wq : (blockIdx.z == 1) ? Wk
                  : (blockIdx.z == 2) ? Wv : Wo;
  _Float16* WT = dst + (size_t)blockIdx.z * 1024 * 1024;
  __shared__ float t[32][33];
  const int tx = threadIdx.x & 31;
  const int ty = threadIdx.x >> 5;
  const int k0 = blockIdx.x * 32, n0 = blockIdx.y * 32;
#pragma unroll
  for (int j = 0; j < 4; ++j)
    t[ty + j * 8][tx] = W[(size_t)(k0 + ty + j * 8) * 1024 + n0 + tx];
  __syncthreads();
#pragma unroll
  for (int j = 0; j < 4; ++j)
    WT[(size_t)(n0 + ty + j * 8) * 1024 + k0 + tx] = (_Float16)t[tx][ty + j * 8];
}

// ---------------------------------------------------------------------------
// K2/K4: GEMM C[8192,1024] = A[8192,1024] @ W + bias, fp16 MFMA, fp32 accum.
// (round-13 form — reg-staged A w/ packed cvt; gload_lds variants were
// falsified twice, r12/r14)
// OP 0: A=query fp32, out = half q_up [B,H,S,64], (acc+bias)*0.125*log2(e)
// OP 1: A=key   fp32, out = half k_up [B,H,S,64]
// OP 2: A=value fp32, out = half vT   [B,H,64,S], KEY INDEX BITS 2<->3
//       SWAPPED (k-axis permutation so attn's PV B-frags need no exchange)
// OP 3: A=ctx  fp16,  out = float d_out [8192,1024]
// ---------------------------------------------------------------------------
template <int OP>
__global__ __launch_bounds__(256) void gemm_k(
    const void* __restrict__ Ap, const _Float16* __restrict__ BT,
    const float* __restrict__ bias, void* __restrict__ Cp)
{
  __shared__ __align__(16) _Float16 As[128 * 64];
  __shared__ __align__(16) _Float16 Bs[128 * 64];
  const int tid = threadIdx.x;
  const int lane = tid & 63;
  const int wv = tid >> 6;
  const int m0 = blockIdx.x * 128;
  const int n0 = blockIdx.y * 128;
  const int wr = (wv >> 1) * 64;
  const int wc = (wv & 1) * 64;

  floatx4 acc[4][4];
#pragma unroll
  for (int i = 0; i < 4; ++i)
#pragma unroll
    for (int j = 0; j < 4; ++j) acc[i][j] = (floatx4){0.f, 0.f, 0.f, 0.f};

  char* AsB = (char*)As;
  char* BsB = (char*)Bs;

  for (int ko = 0; ko < 1024; ko += 64) {
#pragma unroll
    for (int r = 0; r < 4; ++r) {
      const int idx = (r * 256 + tid) * 8;   // half index within 128x64 tile
      const int row = idx >> 6;
      const int colh = idx & 63;
      const int dstb = row * 128 + ((colh * 2) ^ ((row & 7) << 4));
      if (OP == 3) {
        const _Float16* s = (const _Float16*)Ap + (size_t)(m0 + row) * 1024 + ko + colh;
        *(half8*)(AsB + dstb) = *(const half8*)s;
      } else {
        const float* s = (const float*)Ap + (size_t)(m0 + row) * 1024 + ko + colh;
        floatx4 v0 = *(const floatx4*)s;
        floatx4 v1 = *(const floatx4*)(s + 4);
        union { half8 v; unsigned int u[4]; } pk;
        pk.u[0] = __builtin_bit_cast(unsigned int, __builtin_amdgcn_cvt_pkrtz(v0[0], v0[1]));
        pk.u[1] = __builtin_bit_cast(unsigned int, __builtin_amdgcn_cvt_pkrtz(v0[2], v0[3]));
        pk.u[2] = __builtin_bit_cast(unsigned int, __builtin_amdgcn_cvt_pkrtz(v1[0], v1[1]));
        pk.u[3] = __builtin_bit_cast(unsigned int, __builtin_amdgcn_cvt_pkrtz(v1[2], v1[3]));
        *(half8*)(AsB + dstb) = pk.v;
      }
      const _Float16* bs = BT + (size_t)(n0 + row) * 1024 + ko + colh;
      *(half8*)(BsB + dstb) = *(const half8*)bs;
    }
    __syncthreads();
#pragma unroll
    for (int kk = 0; kk < 64; kk += 32) {
      half8 af[4], bf[4];
#pragma unroll
      for (int mi = 0; mi < 4; ++mi) {
        const int row = wr + mi * 16 + (lane & 15);
        const int cb = (kk + (lane >> 4) * 8) * 2;
        af[mi] = *(const half8*)(AsB + row * 128 + (cb ^ ((row & 7) << 4)));
      }
#pragma unroll
      for (int ni = 0; ni < 4; ++ni) {
        const int row = wc + ni * 16 + (lane & 15);
        const int cb = (kk + (lane >> 4) * 8) * 2;
        bf[ni] = *(const half8*)(BsB + row * 128 + (cb ^ ((row & 7) << 4)));
      }
#pragma unroll
      for (int mi = 0; mi < 4; ++mi)
#pragma unroll
        for (int ni = 0; ni < 4; ++ni)
          acc[mi][ni] = MFMA16(af[mi], bf[ni], acc[mi][ni]);
    }
    __syncthreads();
  }

  // Epilogue. C/D layout: col = lane&15, row = (lane>>4)*4 + i
#pragma unroll
  for (int ni = 0; ni < 4; ++ni) {
    const int nn = n0 + wc + ni * 16 + (lane & 15);
    const float bvv = bias[nn];
#pragma unroll
    for (int mi = 0; mi < 4; ++mi) {
      floatx4 c = acc[mi][ni];
#pragma unroll
      for (int i = 0; i < 4; ++i) {
        const int mm = m0 + wr + mi * 16 + (lane >> 4) * 4 + i;
        float val = c[i] + bvv;
        if (OP == 0) val *= 0.1803368801111204f;   // (1/8) * log2(e)
        if (OP == 0 || OP == 1) {
          _Float16* o = (_Float16*)Cp;
          const size_t off =
              ((size_t)((mm >> 11) * 16 + (nn >> 6)) * 2048 + (mm & 2047)) * 64 + (nn & 63);
          o[off] = (_Float16)val;
        } else if (OP == 2) {
          _Float16* o = (_Float16*)Cp;
          // key index with bits 2<->3 swapped (k-axis permutation for PV)
          const int mmp = (mm & ~0xC) | ((mm & 4) << 1) | ((mm & 8) >> 1);
          const size_t off =
              ((size_t)((mm >> 11) * 16 + (nn >> 6)) * 64 + (nn & 63)) * 2048 + (mmp & 2047);
          o[off] = (_Float16)val;
        } else {
          float* o = (float*)Cp;
          o[(size_t)mm * 1024 + nn] = val;
        }
      }
    }
  }
}

// ---------------------------------------------------------------------------
// K3: flash attention, 32x32x16 MFMA, fixed-max in-register softmax.
// 8 WAVES/block (512 thr), each wave owns ONE 32-row q-tile -> accumulator
// halves to 32 regs/wave (unified VGPR+AGPR <= 128 bucket -> 4 waves/SIMD).
// Same 16KB K/V LDS tiles now amortized over 8 waves; staging split: waves
// 0-3 stage K, waves 4-7 stage V (identical 256-thread coalesced patterns).
// KV step 32, double-buffered, 1 barrier/step. COMPUTE body identical to
// round 13 (fixed-max log2 softmax, k-permuted PV, no cross-lane exchange).
// ---------------------------------------------------------------------------
__global__ __launch_bounds__(512) void attn_k(
    const _Float16* __restrict__ q_up, const _Float16* __restrict__ k_up,
    const _Float16* __restrict__ vT, const unsigned int* __restrict__ pmaskT,
    _Float16* __restrict__ ctx)
{
  const int tid = threadIdx.x;
  const int lane = tid & 63;
  const int wv = tid >> 6;                 // 0..7
  // XCD-locality swizzle (bijective over 512 = 8 xcd * 8 heads * 8 qchunks)
  const int bid = blockIdx.x;
  const int xcd = bid & 7;
  const int slot = bid >> 3;
  const int bh = xcd * 8 + (slot & 7);
  const int qc = slot >> 3;
  const int b = bh >> 4;
  const int h = bh & 15;
  const int l31 = lane & 31;
  const int hi = lane >> 5;
  const int qw = qc * 256 + wv * 32;       // wave's 32 q-rows

  __shared__ __align__(16) _Float16 Kl[2][32 * 64];   // 2 x 4KB
  __shared__ __align__(16) _Float16 Vl[2][64 * 32];   // 2 x 4KB

  const _Float16* qb = q_up + ((size_t)bh * 2048 + qw) * 64;
  const _Float16* kb = k_up + (size_t)bh * 2048 * 64;
  const _Float16* vb = vT + (size_t)bh * 64 * 2048;
  const unsigned int* mbase = pmaskT + (size_t)(b * 64) * 2048 + qw + l31;

  // staging: waves 0-3 stage K (256 thr x 16B = 4KB), waves 4-7 stage V.
  const bool isK = tid < 256;
  const int st = isK ? tid : tid - 256;
  const int krow = st >> 3, kseg = st & 7;
  const int vrow = st >> 2, vseg = st & 3;
  const int sOff = isK ? (krow * 128 + ((kseg * 16) ^ ((krow & 7) << 4)))
                       : (vrow * 64 + ((vseg * 16) ^ (((vrow >> 1) & 3) << 4)));
  const _Float16* gsrc = isK ? (kb + (size_t)st * 8)
                             : (vb + (size_t)vrow * 2048 + vseg * 8);
  const int gstride = isK ? 2048 : 32;     // halfs per 32-key tile
  char* Lbase = isK ? (char*)Kl : (char*)Vl;
  char* KB = (char*)Kl;
  char* VB = (char*)Vl;

  // Q B-frags (hoisted): col=q=l31, k = kk*16 + hi*8 + j
  half8 qf[4];
#pragma unroll
  for (int kk = 0; kk < 4; ++kk)
    qf[kk] = *(const half8*)(qb + (size_t)l31 * 64 + kk * 16 + hi * 8);

  floatx16 O[2];
#pragma unroll
  for (int dt = 0; dt < 2; ++dt)
#pragma unroll
    for (int r = 0; r < 16; ++r) O[dt][r] = 0.f;
  float lsum = 0.f;

  floatx16 zero16;
#pragma unroll
  for (int r = 0; r < 16; ++r) zero16[r] = 0.f;

  half8 stg;

  auto COMPUTE = [&](int buf, int t) {
    const unsigned int mw = mbase[(size_t)t * 2048];
    // K frags from LDS: row=key=l31, k = kk*16+hi*8+j
    half8 kf[4];
#pragma unroll
    for (int kk = 0; kk < 4; ++kk)
      kf[kk] = *(const half8*)(KB + buf * 4096 + l31 * 128 +
                               ((kk * 32 + hi * 16) ^ ((l31 & 7) << 4)));
    // V frags from LDS: row=d=dt*32+l31, permuted-key halfs kk2*16+hi*8+j
    half8 vf[2][2];
#pragma unroll
    for (int dt = 0; dt < 2; ++dt)
#pragma unroll
      for (int kk2 = 0; kk2 < 2; ++kk2)
        vf[dt][kk2] = *(const half8*)(VB + buf * 4096 + (dt * 32 + l31) * 64 +
                                      ((kk2 * 32 + hi * 16) ^ (((l31 >> 1) & 3) << 4)));

    // QK^T
    floatx16 s;
    __builtin_amdgcn_s_setprio(1);
    {
      floatx16 a;
      a = MFMA32(kf[0], qf[0], zero16);
      a = MFMA32(kf[1], qf[1], a);
      a = MFMA32(kf[2], qf[2], a);
      s = MFMA32(kf[3], qf[3], a);
    }
    __builtin_amdgcn_s_setprio(0);

    // fixed-max softmax: e = masked ? 0 : exp2(s); bit (j+8m+4hi) of mw
    const unsigned int mh = mw >> (4 * hi);
    float e[16];
#pragma unroll
    for (int m = 0; m < 4; ++m) {
      const unsigned int bm = mh >> (8 * m);
#pragma unroll
      for (int j = 0; j < 4; ++j)
        e[4 * m + j] = ((bm >> j) & 1u) ? 0.f : __builtin_amdgcn_exp2f(s[4 * m + j]);
    }
    float u0 = (e[0] + e[1]) + (e[2] + e[3]);
    float u1 = (e[4] + e[5]) + (e[6] + e[7]);
    float u2 = (e[8] + e[9]) + (e[10] + e[11]);
    float u3 = (e[12] + e[13]) + (e[14] + e[15]);
    lsum += (u0 + u1) + (u2 + u3);

    // native packed pairs ARE the PV B-frags (k-axis permuted in vT)
    union { half8 v; unsigned int u[4]; } p0, p1;
    p0.u[0] = __builtin_bit_cast(unsigned int, __builtin_amdgcn_cvt_pkrtz(e[0], e[1]));
    p0.u[1] = __builtin_bit_cast(unsigned int, __builtin_amdgcn_cvt_pkrtz(e[2], e[3]));
    p0.u[2] = __builtin_bit_cast(unsigned int, __builtin_amdgcn_cvt_pkrtz(e[4], e[5]));
    p0.u[3] = __builtin_bit_cast(unsigned int, __builtin_amdgcn_cvt_pkrtz(e[6], e[7]));
    p1.u[0] = __builtin_bit_cast(unsigned int, __builtin_amdgcn_cvt_pkrtz(e[8], e[9]));
    p1.u[1] = __builtin_bit_cast(unsigned int, __builtin_amdgcn_cvt_pkrtz(e[10], e[11]));
    p1.u[2] = __builtin_bit_cast(unsigned int, __builtin_amdgcn_cvt_pkrtz(e[12], e[13]));
    p1.u[3] = __builtin_bit_cast(unsigned int, __builtin_amdgcn_cvt_pkrtz(e[14], e[15]));
    // PV
    __builtin_amdgcn_s_setprio(1);
#pragma unroll
    for (int dt = 0; dt < 2; ++dt) {
      O[dt] = MFMA32(vf[dt][0], p0.v, O[dt]);
      O[dt] = MFMA32(vf[dt][1], p1.v, O[dt]);
    }
    __builtin_amdgcn_s_setprio(0);
  };

  // prologue: stage tile 0 into buf0; fetch tile 1 into regs
  stg = *(const half8*)gsrc;
  *(half8*)(Lbase + sOff) = stg;
  stg = *(const half8*)(gsrc + gstride);
  __syncthreads();

#pragma unroll 1
  for (int t = 0; t < 64; t += 2) {
    {
      *(half8*)(Lbase + 4096 + sOff) = stg;
      const int tn = (t + 2 < 64) ? t + 2 : 0;
      stg = *(const half8*)(gsrc + (size_t)tn * gstride);
      COMPUTE(0, t);
      __syncthreads();
    }
    {
      *(half8*)(Lbase + sOff) = stg;
      const int tn = (t + 3 < 64) ? t + 3 : 0;
      stg = *(const half8*)(gsrc + (size_t)tn * gstride);
      COMPUTE(1, t + 1);
      __syncthreads();
    }
  }

  // Epilogue: cross-half lsum combine, then O^T write.
  // O^T col=q=l31, row d = dt*32 + 8m + 4hi + {0..3} (regs 4m..4m+3)
  {
    const float tot = lsum + __shfl_xor(lsum, 32);
    const float inv = 1.f / tot;
    const size_t rowb = ((size_t)(b * 2048 + qw + l31)) * 1024 + h * 64;
#pragma unroll
    for (int dt = 0; dt < 2; ++dt) {
#pragma unroll
      for (int m = 0; m < 4; ++m) {
        half4 w4;
        w4[0] = (_Float16)(O[dt][4 * m + 0] * inv);
        w4[1] = (_Float16)(O[dt][4 * m + 1] * inv);
        w4[2] = (_Float16)(O[dt][4 * m + 2] * inv);
        w4[3] = (_Float16)(O[dt][4 * m + 3] * inv);
        *(half4*)(ctx + rowb + dt * 32 + 8 * m + 4 * hi) = w4;
      }
    }
  }
}

// ---------------------------------------------------------------------------
// Launch. Workspace (fp16 elems): WT 4M | q_up 8M | k_up 8M | vT 8M | ctx 8M
// | pmaskT 2MB. Total ~74 MB.
// ---------------------------------------------------------------------------
extern "C" void kernel_launch(void* const* d_in, const int* in_sizes, int n_in,
                              void* d_out, int out_size, void* d_ws, size_t ws_size,
                              hipStream_t stream) {
  const float* key   = (const float*)d_in[0];
  const float* value = (const float*)d_in[1];
  const float* query = (const float*)d_in[2];
  const int*   mask  = (const int*)d_in[3];     // bool -> int32 per harness
  const float* Wq = (const float*)d_in[4];
  const float* bq = (const float*)d_in[5];
  const float* Wk = (const float*)d_in[6];
  const float* bk = (const float*)d_in[7];
  const float* Wv = (const float*)d_in[8];
  const float* bv = (const float*)d_in[9];
  const float* Wo = (const float*)d_in[10];
  const float* bo = (const float*)d_in[11];

  _Float16* wsp = (_Float16*)d_ws;
  _Float16* WT   = wsp;
  _Float16* q_up = wsp + (size_t)4 * 1024 * 1024;
  _Float16* k_up = q_up + (size_t)8192 * 1024;
  _Float16* vT   = k_up + (size_t)8192 * 1024;
  _Float16* ctx  = vT + (size_t)8192 * 1024;
  unsigned int* pmaskT = (unsigned int*)(ctx + (size_t)8192 * 1024);

  maskpack<<<dim3(2048), 256, 0, stream>>>(mask, pmaskT);
  wconv<<<dim3(32, 32, 4), 256, 0, stream>>>(Wq, Wk, Wv, Wo, WT);
  gemm_k<0><<<dim3(64, 8), 256, 0, stream>>>(query, WT, bq, q_up);
  gemm_k<1><<<dim3(64, 8), 256, 0, stream>>>(key, WT + (size_t)1024 * 1024, bk, k_up);
  gemm_k<2><<<dim3(64, 8), 256, 0, stream>>>(value, WT + (size_t)2 * 1024 * 1024, bv, vT);
  attn_k<<<dim3(512), 512, 0, stream>>>(q_up, k_up, vT, pmaskT, ctx);
  gemm_k<3><<<dim3(64, 8), 256, 0, stream>>>(ctx, WT + (size_t)3 * 1024 * 1024, bo, (float*)d_out);
}